// Round 2
// baseline (645.374 us; speedup 1.0000x reference)
//
#include <hip/hip_runtime.h>

#define B_SZ   2048
#define V_SZ   50257
#define TD     2048
#define NIN    128
#define NOUT   128
#define NRECV  1628
#define KDEG   45
#define KPAD   48
#define HPL    300
#define VALSN  1632   // 1630 rounded up

typedef __bf16 bf16x8 __attribute__((ext_vector_type(8)));
typedef float  floatx16 __attribute__((ext_vector_type(16)));

__device__ __forceinline__ unsigned short f2bf(float f) {
  unsigned u = __float_as_uint(f);
  u += 0x7fffu + ((u >> 16) & 1u);
  return (unsigned short)(u >> 16);
}

// ---------------- prep: gather+convert+init, one fused kernel ----------------
#define P0 1048576
#define P1 1608224
#define P2 65536
#define P3 65536
#define P4 78144
#define PREP_TOTAL (P0 + P1 + P2 + P3 + P4)   // 2866016
#define PREP_BLOCKS ((PREP_TOTAL + 255) / 256) // 11196

__global__ __launch_bounds__(256) void prep_kernel(
    const int* __restrict__ ids, const float* __restrict__ temb,
    const float* __restrict__ in_w, const float* __restrict__ in_b,
    const int* __restrict__ src, const float* __restrict__ rw,
    const float* __restrict__ out_w,
    unsigned short* __restrict__ flatb, unsigned short* __restrict__ inwb,
    unsigned short* __restrict__ outwb, float* __restrict__ x,
    int* __restrict__ iw) {
  int i = blockIdx.x * 256 + threadIdx.x;
  if (i < P0) {
    int bt = i >> 3, d4 = i & 7;
    int id = ids[bt];
    float4 v = *(const float4*)(temb + id * 32 + d4 * 4);
    ushort4 o; o.x = f2bf(v.x); o.y = f2bf(v.y); o.z = f2bf(v.z); o.w = f2bf(v.w);
    *(ushort4*)(flatb + (size_t)i * 4) = o;
    return;
  }
  i -= P0;
  if (i < P1) {
    float4 v = ((const float4*)out_w)[i];
    ushort4 o; o.x = f2bf(v.x); o.y = f2bf(v.y); o.z = f2bf(v.z); o.w = f2bf(v.w);
    *(ushort4*)(outwb + (size_t)i * 4) = o;
    return;
  }
  i -= P1;
  if (i < P2) {
    float4 v = ((const float4*)in_w)[i];
    ushort4 o; o.x = f2bf(v.x); o.y = f2bf(v.y); o.z = f2bf(v.z); o.w = f2bf(v.w);
    *(ushort4*)(inwb + (size_t)i * 4) = o;
    return;
  }
  i -= P2;
  if (i < P3) {
    float4 bv = ((const float4*)in_b)[i & 31];
    ((float4*)x)[i] = bv;
    return;
  }
  i -= P3;
  if (i < P4) {
    int r = i / KPAD, k = i - r * KPAD;
    int idx = 0; unsigned wb = 0;
    if (k < KDEG) {
      idx = src[r * KDEG + k];
      wb = __float_as_uint(rw[r * KDEG + k]);
    }
    iw[(size_t)i * 2] = idx;
    iw[(size_t)i * 2 + 1] = (int)wb;
  }
}

// ---------------- gemm1: x += flat @ in_w^T  (split-K=4, MFMA 32x32x16) -----
__global__ __launch_bounds__(256) void gemm1_kernel(
    const __bf16* __restrict__ flatb, const __bf16* __restrict__ inwb,
    float* __restrict__ x) {
  int tid = threadIdx.x;
  int wv = tid >> 6, lane = tid & 63;
  int row = lane & 31, half = lane >> 5;
  int m0 = blockIdx.x * 32;
  int n0 = wv * 32;
  int k0 = blockIdx.y * 512;
  const __bf16* ap = flatb + (size_t)(m0 + row) * TD + k0 + half * 8;
  const __bf16* bp = inwb + (size_t)(n0 + row) * TD + k0 + half * 8;
  floatx16 acc = (floatx16)0.0f;
#pragma unroll 8
  for (int s = 0; s < 32; ++s) {
    bf16x8 a = *(const bf16x8*)(ap + s * 16);
    bf16x8 b = *(const bf16x8*)(bp + s * 16);
    acc = __builtin_amdgcn_mfma_f32_32x32x16_bf16(a, b, acc, 0, 0, 0);
  }
  int col = n0 + row;
#pragma unroll
  for (int r = 0; r < 16; ++r) {
    int mrow = (r & 3) + 8 * (r >> 2) + 4 * half;
    atomicAdd(&x[(m0 + mrow) * NIN + col], acc[r]);
  }
}

// ---------------- rwnn: sparse DAG forward, 8 batch elems / block ------------
__global__ __launch_bounds__(256) void rwnn_kernel(
    const float* __restrict__ x, const int* __restrict__ iw,
    unsigned short* __restrict__ hb) {
  __shared__ float vals[VALSN * 8];   // [node][batch8], 52224 B
  int tid = threadIdx.x;
  int b0 = blockIdx.x * 8;
  {
    int p = tid & 7, n = tid >> 3;           // n in 0..31
    for (int nn = n; nn < NIN; nn += 32)
      vals[nn * 8 + p] = x[(b0 + p) * NIN + nn];
    if (tid < 16) vals[(NIN + (tid >> 3)) * 8 + (tid & 7)] = 1.0f;
  }
  __syncthreads();
  int g = tid >> 1;          // 0..127 node group
  int pb = (tid & 1) * 4;    // batch sub-quad 0 or 4
  int base = NIN + 2;        // 130
  int off = 0;
  for (int layer = 0; layer < 5; ++layer) {
    for (int r = g; r < HPL; r += 128) {
      const int4* q4 = (const int4*)(iw) + (size_t)(off + r) * (KPAD / 2);
      float s0 = 0.f, s1 = 0.f, s2 = 0.f, s3 = 0.f;
      // KPAD=48 (idx,w) pairs = 96 ints = 24 int4s per row; 2 pairs per int4.
#pragma unroll
      for (int k4 = 0; k4 < KPAD / 2; ++k4) {
        int4 q = q4[k4];
        float4 v0 = *(const float4*)(&vals[q.x * 8 + pb]);
        float w0 = __int_as_float(q.y);
        s0 += v0.x * w0; s1 += v0.y * w0; s2 += v0.z * w0; s3 += v0.w * w0;
        float4 v1 = *(const float4*)(&vals[q.z * 8 + pb]);
        float w1 = __int_as_float(q.w);
        s0 += v1.x * w1; s1 += v1.y * w1; s2 += v1.z * w1; s3 += v1.w * w1;
      }
      float4 o;
      o.x = tanhf(s0); o.y = tanhf(s1); o.z = tanhf(s2); o.w = tanhf(s3);
      *(float4*)(&vals[(base + r) * 8 + pb]) = o;
    }
    __syncthreads();
    off += HPL; base += HPL;
  }
  // output layer: rows off..off+127 (off == 1500), every g does exactly one
  {
    int r = g;
    const int4* q4 = (const int4*)(iw) + (size_t)(off + r) * (KPAD / 2);
    float s0 = 0.f, s1 = 0.f, s2 = 0.f, s3 = 0.f;
#pragma unroll
    for (int k4 = 0; k4 < KPAD / 2; ++k4) {
      int4 q = q4[k4];
      float4 v0 = *(const float4*)(&vals[q.x * 8 + pb]);
      float w0 = __int_as_float(q.y);
      s0 += v0.x * w0; s1 += v0.y * w0; s2 += v0.z * w0; s3 += v0.w * w0;
      float4 v1 = *(const float4*)(&vals[q.z * 8 + pb]);
      float w1 = __int_as_float(q.w);
      s0 += v1.x * w1; s1 += v1.y * w1; s2 += v1.z * w1; s3 += v1.w * w1;
    }
    hb[(b0 + pb + 0) * NOUT + r] = f2bf(tanhf(s0));
    hb[(b0 + pb + 1) * NOUT + r] = f2bf(tanhf(s1));
    hb[(b0 + pb + 2) * NOUT + r] = f2bf(tanhf(s2));
    hb[(b0 + pb + 3) * NOUT + r] = f2bf(tanhf(s3));
  }
}

// ---------------- gemm3: logits = h @ out_w^T + out_b  (MFMA 32x32x16) ------
__global__ __launch_bounds__(256) void gemm3_kernel(
    const __bf16* __restrict__ h, const __bf16* __restrict__ wv,
    const float* __restrict__ out_b, float* __restrict__ out) {
  int tid = threadIdx.x;
  int wvid = tid >> 6, lane = tid & 63;
  int row = lane & 31, half = lane >> 5;
  int m0 = blockIdx.x * 32;
  int v0 = blockIdx.y * 128 + wvid * 32;
  int vr = v0 + row;
  int vc = vr < V_SZ ? vr : V_SZ - 1;
  const __bf16* ap = h + (size_t)(m0 + row) * NOUT + half * 8;
  const __bf16* bp = wv + (size_t)vc * NOUT + half * 8;
  floatx16 acc = (floatx16)0.0f;
#pragma unroll
  for (int s = 0; s < 8; ++s) {
    bf16x8 a = *(const bf16x8*)(ap + s * 16);
    bf16x8 b = *(const bf16x8*)(bp + s * 16);
    acc = __builtin_amdgcn_mfma_f32_32x32x16_bf16(a, b, acc, 0, 0, 0);
  }
  if (vr < V_SZ) {
    float bias = out_b[vr];
#pragma unroll
    for (int r = 0; r < 16; ++r) {
      int mrow = (r & 3) + 8 * (r >> 2) + 4 * half;
      out[(size_t)(m0 + mrow) * V_SZ + vr] = acc[r] + bias;
    }
  }
}

// ---------------- launch -----------------------------------------------------
extern "C" void kernel_launch(void* const* d_in, const int* in_sizes, int n_in,
                              void* d_out, int out_size, void* d_ws, size_t ws_size,
                              hipStream_t stream) {
  const int*   ids   = (const int*)d_in[0];
  const float* temb  = (const float*)d_in[1];
  const float* in_w  = (const float*)d_in[2];
  const float* in_b  = (const float*)d_in[3];
  const int*   src   = (const int*)d_in[4];
  const float* rw    = (const float*)d_in[5];
  const float* out_w = (const float*)d_in[6];
  const float* out_b = (const float*)d_in[7];
  float* out = (float*)d_out;

  char* ws = (char*)d_ws;
  unsigned short* flatb = (unsigned short*)(ws);
  unsigned short* inwb  = (unsigned short*)(ws + 8388608);
  unsigned short* outwb = (unsigned short*)(ws + 8912896);
  float*          x     = (float*)(ws + 21778688);
  unsigned short* hb    = (unsigned short*)(ws + 22827264);
  int*            iw    = (int*)(ws + 23351552);

  prep_kernel<<<PREP_BLOCKS, 256, 0, stream>>>(ids, temb, in_w, in_b, src, rw,
                                               out_w, flatb, inwb, outwb, x, iw);
  gemm1_kernel<<<dim3(64, 4), 256, 0, stream>>>((const __bf16*)flatb,
                                                (const __bf16*)inwb, x);
  rwnn_kernel<<<256, 256, 0, stream>>>(x, iw, hb);
  gemm3_kernel<<<dim3(64, 393), 256, 0, stream>>>((const __bf16*)hb,
                                                  (const __bf16*)outwb, out_b, out);
}